// Round 2
// baseline (3027.668 us; speedup 1.0000x reference)
//
#include <hip/hip_runtime.h>
#include <stdint.h>

#define BB 64
#define TT 2048
#define KK 128

__device__ __forceinline__ float waveMax(float v) {
#pragma unroll
    for (int off = 32; off; off >>= 1) v = fmaxf(v, __shfl_xor(v, off, 64));
    return v;
}
__device__ __forceinline__ float waveSum(float v) {
#pragma unroll
    for (int off = 32; off; off >>= 1) v += __shfl_xor(v, off, 64);
    return v;
}
__device__ __forceinline__ int waveSumI(int v) {
#pragma unroll
    for (int off = 32; off; off >>= 1) v += __shfl_xor(v, off, 64);
    return v;
}

// One block per batch b. Waves 0-1: supervised chain; waves 2-3: unsupervised.
// Thread owns output state k = tid&127; W[:,k] in 128 VGPRs.
// Bool inputs (mask/target/forbidden) are int32 per harness convention.
extern "C" __global__ __launch_bounds__(256, 1)
void crf_fused_kernel(const float* __restrict__ em,
                      const int* __restrict__ mask,
                      const int* __restrict__ tgt,
                      const float* __restrict__ trans,
                      const float* __restrict__ start,
                      const int* __restrict__ forb,
                      float* __restrict__ out)
{
    const int tid = threadIdx.x;
    const int k = tid & (KK - 1);
    const int chain = tid >> 7;            // 0 = supervised, 1 = unsupervised
    const bool sup = (chain == 0);         // wave-uniform
    const int cw = (tid >> 6) & 1;         // wave index within chain
    const int lane = tid & 63;
    const int b = blockIdx.x;

    __shared__ __align__(16) float eLDS[2][2][KK];  // [chain][buf][k]
    __shared__ float wmLDS[2][2][2];                // [chain][buf][cw]
    __shared__ float redLDS[2][2];                  // [chain][cw]
    __shared__ float zLDS[2];
    __shared__ int lenLDS;

    // ---- length = sum of int32 mask row (values 0/1) ----
    if (tid == 0) lenLDS = 0;
    const int4* __restrict__ mrow = (const int4*)(mask + (size_t)b * TT);
    const int4 m0 = mrow[2 * tid], m1 = mrow[2 * tid + 1];
    int psum = m0.x + m0.y + m0.z + m0.w + m1.x + m1.y + m1.z + m1.w;
    psum = waveSumI(psum);
    __syncthreads();
    if (lane == 0) atomicAdd(&lenLDS, psum);

    const float st = start[k];
    const float* __restrict__ emrow = em + (size_t)b * TT * KK;
    const int* __restrict__ trow = tgt + (size_t)b * TT * KK;

    // ---- W column: W[i] = forbidden ? 0 : exp(trans[i][k]) (time-invariant) ----
    float W[KK];
#pragma unroll
    for (int i = 0; i < KK; ++i) {
        const float tv = trans[i * KK + k];
        W[i] = forb[i * KK + k] ? 0.0f : __expf(tv);
    }

    // ---- t = 0: alpha0, exact max rescale ----
    float v0 = emrow[k];
    if (sup && !trow[k]) v0 = -100000.0f;
    v0 += st;
    const float wm = waveMax(v0);
    if (lane == 0) redLDS[chain][cw] = wm;
    __syncthreads();
    const int len = lenLDS;                         // uniform, in [1024, 2048]
    const float M0 = fmaxf(redLDS[chain][0], redLDS[chain][1]);
    double M = (double)M0;                          // running log-scale (fp64)
    const float u0 = v0 - M0;
    eLDS[chain][0][k] = __expf(u0);
    const float wmu0 = waveMax(u0);
    if (lane == 0) wmLDS[chain][0][cw] = wmu0;
    __syncthreads();

    auto bival = [&](int t) -> float {
        float e0 = emrow[(size_t)t * KK + k];
        if (sup) { if (!trow[(size_t)t * KK + k]) e0 = -100000.0f; }
        return e0 + st;
    };

    // emission/target prefetch, depth 2
    float biA = (len > 1) ? bival(1) : 0.0f;
    float biB = (len > 2) ? bival(2) : 0.0f;

    for (int t = 1; t < len; ++t) {
        const int p = (t - 1) & 1;
        // delayed exact max from step t-1 (off critical path; bounded: M_{t+1}
        // telescopes to max_k alpha_t, so |max u| <~ 11 -> no fp32 overflow)
        const float mh = fmaxf(wmLDS[chain][p][0], wmLDS[chain][p][1]);
        const float biN = (t + 2 < len) ? bival(t + 2) : 0.0f;

        // matvec: s_k = sum_i e[i] * W[i][k]; e via LDS broadcast float4 reads
        const float4* __restrict__ ev = (const float4*)eLDS[chain][p];
        float sA = 0.f, sB = 0.f, sC = 0.f, sD = 0.f;
#pragma unroll
        for (int i4 = 0; i4 < KK / 4; ++i4) {
            const float4 e4 = ev[i4];
            sA = fmaf(e4.x, W[4 * i4 + 0], sA);
            sB = fmaf(e4.y, W[4 * i4 + 1], sB);
            sC = fmaf(e4.z, W[4 * i4 + 2], sC);
            sD = fmaf(e4.w, W[4 * i4 + 3], sD);
        }
        const float s = (sA + sB) + (sC + sD);

        const float u2 = __logf(s) + biA - mh;   // log(0) = -inf for dead states: ok
        M += (double)mh;
        const float e2 = __expf(u2);
        eLDS[chain][p ^ 1][k] = e2;
        const float wmu2 = waveMax(u2);
        if (lane == 0) wmLDS[chain][p ^ 1][cw] = wmu2;
        biA = biB; biB = biN;
        __syncthreads();   // single barrier/step (double-buffered e/wm)
    }

    // ---- z = M + log(sum_k e_k) at t = len-1; out = z_sup - z_unsup ----
    const int pf = (len - 1) & 1;
    const float sm = waveSum(eLDS[chain][pf][k]);
    if (lane == 0) redLDS[chain][cw] = sm;
    __syncthreads();
    if (lane == 0 && cw == 0)
        zLDS[chain] = (float)(M + (double)__logf(redLDS[chain][0] + redLDS[chain][1]));
    __syncthreads();
    if (tid == 0) out[b] = zLDS[0] - zLDS[1];
}

extern "C" void kernel_launch(void* const* d_in, const int* in_sizes, int n_in,
                              void* d_out, int out_size, void* d_ws, size_t ws_size,
                              hipStream_t stream) {
    const float* em    = (const float*)d_in[0];
    const int*   mask  = (const int*)d_in[1];
    const int*   tgt   = (const int*)d_in[2];
    const float* trans = (const float*)d_in[3];
    const float* start = (const float*)d_in[4];
    const int*   forb  = (const int*)d_in[5];

    crf_fused_kernel<<<BB, 256, 0, stream>>>(em, mask, tgt, trans, start, forb,
                                             (float*)d_out);
}

// Round 3
// 2305.178 us; speedup vs baseline: 1.3134x; 1.3134x over previous
//
#include <hip/hip_runtime.h>
#include <stdint.h>

#define BB 64
#define TT 2048
#define KK 128

typedef float f32x16 __attribute__((ext_vector_type(16)));

__device__ __forceinline__ float waveMax(float v) {
#pragma unroll
    for (int off = 32; off; off >>= 1) v = fmaxf(v, __shfl_xor(v, off, 64));
    return v;
}
__device__ __forceinline__ float waveSum(float v) {
#pragma unroll
    for (int off = 32; off; off >>= 1) v += __shfl_xor(v, off, 64);
    return v;
}
__device__ __forceinline__ int waveSumI(int v) {
#pragma unroll
    for (int off = 32; off; off >>= 1) v += __shfl_xor(v, off, 64);
    return v;
}

// 16 FMAs: e[16q..16q+15] (broadcast from LDS) * W-vector Wv, 4 accumulators.
#define GRP(Wv, q) { \
    const float4 ea = ev[4*(q)+0]; \
    s0 = fmaf(ea.x, Wv[0],  s0); s1 = fmaf(ea.y, Wv[1],  s1); \
    s2 = fmaf(ea.z, Wv[2],  s2); s3 = fmaf(ea.w, Wv[3],  s3); \
    const float4 eb = ev[4*(q)+1]; \
    s0 = fmaf(eb.x, Wv[4],  s0); s1 = fmaf(eb.y, Wv[5],  s1); \
    s2 = fmaf(eb.z, Wv[6],  s2); s3 = fmaf(eb.w, Wv[7],  s3); \
    const float4 ec = ev[4*(q)+2]; \
    s0 = fmaf(ec.x, Wv[8],  s0); s1 = fmaf(ec.y, Wv[9],  s1); \
    s2 = fmaf(ec.z, Wv[10], s2); s3 = fmaf(ec.w, Wv[11], s3); \
    const float4 ed = ev[4*(q)+3]; \
    s0 = fmaf(ed.x, Wv[12], s0); s1 = fmaf(ed.y, Wv[13], s1); \
    s2 = fmaf(ed.z, Wv[14], s2); s3 = fmaf(ed.w, Wv[15], s3); }

// One block per chain c in [0,128): c<64 supervised (batch b=c&63), else unsup.
// 256 threads: k = tid&127 (output state), h = tid>>7 (i-half).
// Each thread holds W[h*64 .. h*64+63][k] in 4 named ext-vector registers
// (guaranteed SSA -> VGPRs; round-2's float W[128] array went to scratch:
// FETCH_SIZE 51 GB, VGPR=96).
extern "C" __global__ __launch_bounds__(256, 1)
void crf_chain_kernel(const float* __restrict__ em,
                      const int* __restrict__ mask,
                      const int* __restrict__ tgt,
                      const float* __restrict__ trans,
                      const float* __restrict__ start,
                      const int* __restrict__ forb,
                      float* __restrict__ zbuf)
{
    const int tid  = threadIdx.x;
    const int k    = tid & (KK - 1);
    const int h    = tid >> 7;          // 0: glue half, 1: partial-only half
    const int wv   = tid >> 6;          // wave 0..3 (h0 = waves 0,1)
    const int lane = tid & 63;
    const int c    = blockIdx.x;
    const int b    = c & (BB - 1);
    const bool sup = (c < BB);

    __shared__ __align__(16) float eLDS[2][KK];   // double-buffered exp(u)
    __shared__ float pLDS[KK];                    // h1 partial sums
    __shared__ float wmLDS[2][2];                 // delayed per-wave max(u)
    __shared__ float redLDS[2];
    __shared__ int lenLDS;

    // ---- length = sum of int32 mask row ----
    if (tid == 0) lenLDS = 0;
    const int4* __restrict__ mrow4 = (const int4*)(mask + (size_t)b * TT);
    const int4 mm0 = mrow4[2 * tid], mm1 = mrow4[2 * tid + 1];
    int ps = mm0.x + mm0.y + mm0.z + mm0.w + mm1.x + mm1.y + mm1.z + mm1.w;
    ps = waveSumI(ps);
    __syncthreads();                    // lenLDS zeroed
    if (lane == 0) atomicAdd(&lenLDS, ps);

    const float st = start[k];
    const float* __restrict__ emrow = em + (size_t)b * TT * KK;
    const int* __restrict__ trow = tgt + (size_t)b * TT * KK;

    // ---- W half-column in named vector registers ----
    const int i0 = h << 6;
    f32x16 W0, W1, W2, W3;
#pragma unroll
    for (int j = 0; j < 16; ++j) {
        const int ia = i0 + j, ib = i0 + 16 + j, ic = i0 + 32 + j, id = i0 + 48 + j;
        W0[j] = forb[ia * KK + k] ? 0.0f : __expf(trans[ia * KK + k]);
        W1[j] = forb[ib * KK + k] ? 0.0f : __expf(trans[ib * KK + k]);
        W2[j] = forb[ic * KK + k] ? 0.0f : __expf(trans[ic * KK + k]);
        W3[j] = forb[id * KK + k] ? 0.0f : __expf(trans[id * KK + k]);
    }

    // ---- t = 0 ----
    float v0 = 0.0f;
    if (h == 0) {
        v0 = emrow[k];
        if (sup && !trow[k]) v0 = -100000.0f;
        v0 += st;
    }
    const float wm0 = waveMax(v0);
    if (h == 0 && lane == 0) redLDS[wv] = wm0;
    __syncthreads();                    // len + redLDS ready
    const int len = lenLDS;             // uniform, in [1024, 2048]
    double M = 0.0;
    if (h == 0) {
        const float M0 = fmaxf(redLDS[0], redLDS[1]);
        M = (double)M0;
        const float u0 = v0 - M0;
        eLDS[0][k] = __expf(u0);
        const float wmu = waveMax(u0);
        if (lane == 0) wmLDS[0][wv] = wmu;
    }
    __syncthreads();                    // eLDS[0], wmLDS[0] ready

    auto bival = [&](int t) -> float {
        float e0 = emrow[(size_t)t * KK + k];
        if (sup) { if (!trow[(size_t)t * KK + k]) e0 = -100000.0f; }
        return e0 + st;
    };

    float biA = 0.0f, biB = 0.0f;
    if (h == 0) {
        biA = (len > 1) ? bival(1) : 0.0f;
        biB = (len > 2) ? bival(2) : 0.0f;
    }

    for (int t = 1; t < len; ++t) {
        const int p = (t - 1) & 1;
        float mh = 0.0f, biN = 0.0f;
        if (h == 0) {
            // delayed exact max of u_{t-1} (off critical path; bounded ~11)
            mh = fmaxf(wmLDS[p][0], wmLDS[p][1]);
            if (t + 2 < len) biN = bival(t + 2);
        }

        // partial matvec over own i-half: 64 FMAs, e via LDS broadcast float4
        const float4* __restrict__ ev = (const float4*)(eLDS[p] + i0);
        float s0 = 0.f, s1 = 0.f, s2 = 0.f, s3 = 0.f;
        GRP(W0, 0) GRP(W1, 1) GRP(W2, 2) GRP(W3, 3)
        const float sh = (s0 + s1) + (s2 + s3);

        if (h == 1) pLDS[k] = sh;
        __syncthreads();                // partials visible

        if (h == 0) {
            const float s = sh + pLDS[k];
            const float u2 = __logf(s) + biA - mh;  // log(0)=-inf for dead states: ok
            M += (double)mh;
            eLDS[p ^ 1][k] = __expf(u2);
            const float wmu = waveMax(u2);
            if (lane == 0) wmLDS[p ^ 1][wv] = wmu;
            biA = biB; biB = biN;
        }
        __syncthreads();                // eLDS[p^1], wmLDS[p^1] visible
    }

    // ---- z = M + log(sum_k e_k) ----
    const int pf = (len - 1) & 1;
    if (h == 0) {
        const float sm = waveSum(eLDS[pf][k]);
        if (lane == 0) redLDS[wv] = sm;
    }
    __syncthreads();
    if (tid == 0)
        zbuf[c] = (float)(M + (double)__logf(redLDS[0] + redLDS[1]));
}

extern "C" __global__ void crf_final_kernel(const float* __restrict__ z,
                                            float* __restrict__ out)
{
    const int b = threadIdx.x;
    out[b] = z[b] - z[b + BB];
}

extern "C" void kernel_launch(void* const* d_in, const int* in_sizes, int n_in,
                              void* d_out, int out_size, void* d_ws, size_t ws_size,
                              hipStream_t stream) {
    const float* em    = (const float*)d_in[0];
    const int*   mask  = (const int*)d_in[1];
    const int*   tgt   = (const int*)d_in[2];
    const float* trans = (const float*)d_in[3];
    const float* start = (const float*)d_in[4];
    const int*   forb  = (const int*)d_in[5];
    float* zbuf = (float*)d_ws;   // 128 per-chain log-partition values

    crf_chain_kernel<<<2 * BB, 256, 0, stream>>>(em, mask, tgt, trans, start, forb, zbuf);
    crf_final_kernel<<<1, BB, 0, stream>>>(zbuf, (float*)d_out);
}

// Round 4
// 2304.216 us; speedup vs baseline: 1.3140x; 1.0004x over previous
//
#include <hip/hip_runtime.h>
#include <stdint.h>

#define BB 64
#define TT 2048
#define KK 128

typedef float f32x16 __attribute__((ext_vector_type(16)));

__device__ __forceinline__ float waveMax(float v) {
#pragma unroll
    for (int off = 32; off; off >>= 1) v = fmaxf(v, __shfl_xor(v, off, 64));
    return v;
}
__device__ __forceinline__ float waveSum(float v) {
#pragma unroll
    for (int off = 32; off; off >>= 1) v += __shfl_xor(v, off, 64);
    return v;
}
__device__ __forceinline__ int waveSumI(int v) {
#pragma unroll
    for (int off = 32; off; off >>= 1) v += __shfl_xor(v, off, 64);
    return v;
}

// 16 FMAs: e[16q..16q+15] (broadcast from LDS) * W-vector Wv, 4 accumulators.
#define GRP(Wv, q) { \
    const float4 ea = ev[4*(q)+0]; \
    s0 = fmaf(ea.x, Wv[0],  s0); s1 = fmaf(ea.y, Wv[1],  s1); \
    s2 = fmaf(ea.z, Wv[2],  s2); s3 = fmaf(ea.w, Wv[3],  s3); \
    const float4 eb = ev[4*(q)+1]; \
    s0 = fmaf(eb.x, Wv[4],  s0); s1 = fmaf(eb.y, Wv[5],  s1); \
    s2 = fmaf(eb.z, Wv[6],  s2); s3 = fmaf(eb.w, Wv[7],  s3); \
    const float4 ec = ev[4*(q)+2]; \
    s0 = fmaf(ec.x, Wv[8],  s0); s1 = fmaf(ec.y, Wv[9],  s1); \
    s2 = fmaf(ec.z, Wv[10], s2); s3 = fmaf(ec.w, Wv[11], s3); \
    const float4 ed = ev[4*(q)+3]; \
    s0 = fmaf(ed.x, Wv[12], s0); s1 = fmaf(ed.y, Wv[13], s1); \
    s2 = fmaf(ed.z, Wv[14], s2); s3 = fmaf(ed.w, Wv[15], s3); }

// One block per chain c in [0,128): c<64 supervised (batch b=c&63), else unsup.
// 256 threads: k = tid&127 (output state), h = tid>>7 (i-half).
// Each thread holds W[h*64 .. h*64+63][k] in 4 f32x16 vectors.
// amdgpu_waves_per_eu(1,1): cap the occupancy TARGET at 1 wave/EU so the
// allocator gets the full 512-VGPR budget. launch_bounds' 2nd arg is only a
// MIN — rounds 2/3 the scheduler spilled W to scratch chasing occupancy
// (VGPR=56 < 64, FETCH 51 GB == spill-reload arithmetic).
extern "C" __global__ __launch_bounds__(256)
__attribute__((amdgpu_waves_per_eu(1, 1)))
void crf_chain_kernel(const float* __restrict__ em,
                      const int* __restrict__ mask,
                      const int* __restrict__ tgt,
                      const float* __restrict__ trans,
                      const float* __restrict__ start,
                      const int* __restrict__ forb,
                      float* __restrict__ zbuf)
{
    const int tid  = threadIdx.x;
    const int k    = tid & (KK - 1);
    const int h    = tid >> 7;          // 0: glue half, 1: partial-only half
    const int wv   = tid >> 6;          // wave 0..3 (h0 = waves 0,1)
    const int lane = tid & 63;
    const int c    = blockIdx.x;
    const int b    = c & (BB - 1);
    const bool sup = (c < BB);

    __shared__ __align__(16) float eLDS[2][KK];   // double-buffered exp(u)
    __shared__ float pLDS[KK];                    // h1 partial sums
    __shared__ float wmLDS[2][2];                 // delayed per-wave max(u)
    __shared__ float redLDS[2];
    __shared__ int lenLDS;

    // ---- length = sum of int32 mask row ----
    if (tid == 0) lenLDS = 0;
    const int4* __restrict__ mrow4 = (const int4*)(mask + (size_t)b * TT);
    const int4 mm0 = mrow4[2 * tid], mm1 = mrow4[2 * tid + 1];
    int ps = mm0.x + mm0.y + mm0.z + mm0.w + mm1.x + mm1.y + mm1.z + mm1.w;
    ps = waveSumI(ps);
    __syncthreads();                    // lenLDS zeroed
    if (lane == 0) atomicAdd(&lenLDS, ps);

    const float st = start[k];
    const float* __restrict__ emrow = em + (size_t)b * TT * KK;
    const int* __restrict__ trow = tgt + (size_t)b * TT * KK;

    // ---- W half-column in named vector registers ----
    const int i0 = h << 6;
    f32x16 W0, W1, W2, W3;
#pragma unroll
    for (int j = 0; j < 16; ++j) {
        const int ia = i0 + j, ib = i0 + 16 + j, ic = i0 + 32 + j, id = i0 + 48 + j;
        W0[j] = forb[ia * KK + k] ? 0.0f : __expf(trans[ia * KK + k]);
        W1[j] = forb[ib * KK + k] ? 0.0f : __expf(trans[ib * KK + k]);
        W2[j] = forb[ic * KK + k] ? 0.0f : __expf(trans[ic * KK + k]);
        W3[j] = forb[id * KK + k] ? 0.0f : __expf(trans[id * KK + k]);
    }

    // ---- t = 0 ----
    float v0 = 0.0f;
    if (h == 0) {
        v0 = emrow[k];
        if (sup && !trow[k]) v0 = -100000.0f;
        v0 += st;
    }
    const float wm0 = waveMax(v0);
    if (h == 0 && lane == 0) redLDS[wv] = wm0;
    __syncthreads();                    // len + redLDS ready
    const int len = lenLDS;             // uniform, in [1024, 2048]
    double M = 0.0;
    if (h == 0) {
        const float M0 = fmaxf(redLDS[0], redLDS[1]);
        M = (double)M0;
        const float u0 = v0 - M0;
        eLDS[0][k] = __expf(u0);
        const float wmu = waveMax(u0);
        if (lane == 0) wmLDS[0][wv] = wmu;
    }
    __syncthreads();                    // eLDS[0], wmLDS[0] ready

    auto bival = [&](int t) -> float {
        float e0 = emrow[(size_t)t * KK + k];
        if (sup) { if (!trow[(size_t)t * KK + k]) e0 = -100000.0f; }
        return e0 + st;
    };

    float biA = 0.0f, biB = 0.0f;
    if (h == 0) {
        biA = (len > 1) ? bival(1) : 0.0f;
        biB = (len > 2) ? bival(2) : 0.0f;
    }

    for (int t = 1; t < len; ++t) {
        const int p = (t - 1) & 1;
        float mh = 0.0f, biN = 0.0f;
        if (h == 0) {
            // delayed exact max of u_{t-1} (off critical path; bounded ~11)
            mh = fmaxf(wmLDS[p][0], wmLDS[p][1]);
            if (t + 2 < len) biN = bival(t + 2);
        }

        // partial matvec over own i-half: 64 FMAs, e via LDS broadcast float4
        const float4* __restrict__ ev = (const float4*)(eLDS[p] + i0);
        float s0 = 0.f, s1 = 0.f, s2 = 0.f, s3 = 0.f;
        GRP(W0, 0) GRP(W1, 1) GRP(W2, 2) GRP(W3, 3)
        const float sh = (s0 + s1) + (s2 + s3);

        if (h == 1) pLDS[k] = sh;
        __syncthreads();                // partials visible

        if (h == 0) {
            const float s = sh + pLDS[k];
            const float u2 = __logf(s) + biA - mh;  // log(0)=-inf for dead states: ok
            M += (double)mh;
            eLDS[p ^ 1][k] = __expf(u2);
            const float wmu = waveMax(u2);
            if (lane == 0) wmLDS[p ^ 1][wv] = wmu;
            biA = biB; biB = biN;
        }
        __syncthreads();                // eLDS[p^1], wmLDS[p^1] visible
    }

    // ---- z = M + log(sum_k e_k) ----
    const int pf = (len - 1) & 1;
    if (h == 0) {
        const float sm = waveSum(eLDS[pf][k]);
        if (lane == 0) redLDS[wv] = sm;
    }
    __syncthreads();
    if (tid == 0)
        zbuf[c] = (float)(M + (double)__logf(redLDS[0] + redLDS[1]));
}

extern "C" __global__ void crf_final_kernel(const float* __restrict__ z,
                                            float* __restrict__ out)
{
    const int b = threadIdx.x;
    out[b] = z[b] - z[b + BB];
}

extern "C" void kernel_launch(void* const* d_in, const int* in_sizes, int n_in,
                              void* d_out, int out_size, void* d_ws, size_t ws_size,
                              hipStream_t stream) {
    const float* em    = (const float*)d_in[0];
    const int*   mask  = (const int*)d_in[1];
    const int*   tgt   = (const int*)d_in[2];
    const float* trans = (const float*)d_in[3];
    const float* start = (const float*)d_in[4];
    const int*   forb  = (const int*)d_in[5];
    float* zbuf = (float*)d_ws;   // 128 per-chain log-partition values

    crf_chain_kernel<<<2 * BB, 256, 0, stream>>>(em, mask, tgt, trans, start, forb, zbuf);
    crf_final_kernel<<<1, BB, 0, stream>>>(zbuf, (float*)d_out);
}

// Round 6
// 2070.762 us; speedup vs baseline: 1.4621x; 1.1127x over previous
//
#include <hip/hip_runtime.h>
#include <stdint.h>

#define BB 64
#define TT 2048
#define KK 128

typedef float f32x16 __attribute__((ext_vector_type(16)));
typedef float f32x2  __attribute__((ext_vector_type(2)));

__device__ __forceinline__ float waveMax(float v) {
#pragma unroll
    for (int off = 32; off; off >>= 1) v = fmaxf(v, __shfl_xor(v, off, 64));
    return v;
}
__device__ __forceinline__ float waveSum(float v) {
#pragma unroll
    for (int off = 32; off; off >>= 1) v += __shfl_xor(v, off, 64);
    return v;
}
__device__ __forceinline__ int waveSumI(int v) {
#pragma unroll
    for (int off = 32; off; off >>= 1) v += __shfl_xor(v, off, 64);
    return v;
}

// LDS-only barrier: waits lgkm only, so global prefetch loads (vmcnt) stay in
// flight across steps. __syncthreads() would drain vmcnt(0) every step.
__device__ __forceinline__ void lds_barrier() {
    asm volatile("s_waitcnt lgkmcnt(0)\n\ts_barrier" ::: "memory");
}

// 16 i's of the matvec as 8 v_pk_fma_f32 (float2 packed FMA), 4 f32x2 accums.
#define GRP(Wv, q) { \
    const float4 ea = ev[4*(q)+0]; \
    const float4 eb = ev[4*(q)+1]; \
    const float4 ec = ev[4*(q)+2]; \
    const float4 ed = ev[4*(q)+3]; \
    a0 = __builtin_elementwise_fma((f32x2){ea.x, ea.y}, (f32x2){Wv[0],  Wv[1]},  a0); \
    a1 = __builtin_elementwise_fma((f32x2){ea.z, ea.w}, (f32x2){Wv[2],  Wv[3]},  a1); \
    a2 = __builtin_elementwise_fma((f32x2){eb.x, eb.y}, (f32x2){Wv[4],  Wv[5]},  a2); \
    a3 = __builtin_elementwise_fma((f32x2){eb.z, eb.w}, (f32x2){Wv[6],  Wv[7]},  a3); \
    a0 = __builtin_elementwise_fma((f32x2){ec.x, ec.y}, (f32x2){Wv[8],  Wv[9]},  a0); \
    a1 = __builtin_elementwise_fma((f32x2){ec.z, ec.w}, (f32x2){Wv[10], Wv[11]}, a1); \
    a2 = __builtin_elementwise_fma((f32x2){ed.x, ed.y}, (f32x2){Wv[12], Wv[13]}, a2); \
    a3 = __builtin_elementwise_fma((f32x2){ed.z, ed.w}, (f32x2){Wv[14], Wv[15]}, a3); }

// One block (128 threads, 2 waves) per chain c: c<64 supervised, else unsup.
// Thread k owns state k; W[:,k] = full column, 8 f32x16 = 128 VGPRs.
// Scale control: BLOCK renormalization — subtract a shift r only at t%4==0,
// where r = max_k log e_{t-2} (measured at iter t-1 top, lag 2). Between
// measurement and application there is no other subtraction, so the residual
// is open-loop growth (<= ~60 nats before next subtract; fp32 exp ceiling 88).
// Round 5's per-step lag-4 subtraction was an unstable feedback loop
// (char poly x^4 - x^3 + 1 has roots outside the unit circle -> oscillating
// overflow -> 0*inf NaN). Per-step: e_next = s * exp(bi - r), NO
// transcendental on the critical path; log feeds only the delayed measure.
extern "C" __global__ __launch_bounds__(128)
__attribute__((amdgpu_waves_per_eu(1, 1)))
void crf_chain_kernel(const float* __restrict__ em,
                      const int* __restrict__ mask,
                      const int* __restrict__ tgt,
                      const float* __restrict__ trans,
                      const float* __restrict__ start,
                      const int* __restrict__ forb,
                      float* __restrict__ zbuf)
{
    const int k    = threadIdx.x;       // state 0..127
    const int wv   = k >> 6;
    const int lane = k & 63;
    const int c    = blockIdx.x;
    const int b    = c & (BB - 1);
    const bool sup = (c < BB);

    __shared__ __align__(16) float eLDS[2][KK];  // double-buffered scaled alpha
    __shared__ __align__(8) float wmB[2];        // per-wave max(log e) at measure
    __shared__ float redLDS[2];
    __shared__ int lenLDS;

    // ---- length = sum of int32 mask row ----
    if (k == 0) lenLDS = 0;
    const int4* __restrict__ mrow4 = (const int4*)(mask + (size_t)b * TT);
    int ps = 0;
#pragma unroll
    for (int q = 0; q < 4; ++q) {
        const int4 m = mrow4[4 * k + q];
        ps += m.x + m.y + m.z + m.w;
    }
    ps = waveSumI(ps);
    __syncthreads();
    if (lane == 0) atomicAdd(&lenLDS, ps);

    const float st = start[k];
    const float* __restrict__ emrow = em + (size_t)b * TT * KK;
    const int* __restrict__ trow = tgt + (size_t)b * TT * KK;

    // ---- W full column in 8 f32x16; Wv[j] = W[v*16+j][k] (pairs adjacent) ----
    f32x16 W0, W1, W2, W3, W4, W5, W6, W7;
#pragma unroll
    for (int j = 0; j < 16; ++j) {
        W0[j] = forb[(j      ) * KK + k] ? 0.0f : __expf(trans[(j      ) * KK + k]);
        W1[j] = forb[(j +  16) * KK + k] ? 0.0f : __expf(trans[(j +  16) * KK + k]);
        W2[j] = forb[(j +  32) * KK + k] ? 0.0f : __expf(trans[(j +  32) * KK + k]);
        W3[j] = forb[(j +  48) * KK + k] ? 0.0f : __expf(trans[(j +  48) * KK + k]);
        W4[j] = forb[(j +  64) * KK + k] ? 0.0f : __expf(trans[(j +  64) * KK + k]);
        W5[j] = forb[(j +  80) * KK + k] ? 0.0f : __expf(trans[(j +  80) * KK + k]);
        W6[j] = forb[(j +  96) * KK + k] ? 0.0f : __expf(trans[(j +  96) * KK + k]);
        W7[j] = forb[(j + 112) * KK + k] ? 0.0f : __expf(trans[(j + 112) * KK + k]);
    }

    // ---- t = 0: exact max rescale (one-time) ----
    float v0 = emrow[k];
    if (sup && !trow[k]) v0 = -100000.0f;
    v0 += st;
    const float wm0 = waveMax(v0);
    if (lane == 0) redLDS[wv] = wm0;
    __syncthreads();
    const int len = lenLDS;                      // uniform, in [1024, 2048]
    const float M0 = fmaxf(redLDS[0], redLDS[1]);
    double M = (double)M0;                       // running log-scale, fp64
    float eNew = __expf(v0 - M0);
    eLDS[0][k] = eNew;

    auto bival = [&](int t) -> float {
        float e0 = emrow[(size_t)t * KK + k];
        if (sup) { if (!trow[(size_t)t * KK + k]) e0 = -100000.0f; }
        return e0 + st;
    };

    // bi pipeline, depth 4
    float biA = (1 <= len - 1) ? bival(1) : 0.0f;
    float biB = (2 <= len - 1) ? bival(2) : 0.0f;
    float biC = (3 <= len - 1) ? bival(3) : 0.0f;
    float biD = (4 <= len - 1) ? bival(4) : 0.0f;

    float sPrev = 1.0f, baPrev = 0.0f;
    lds_barrier();                               // publish eLDS[0]

#pragma unroll 4
    for (int t = 1; t < len; ++t) {
        const int p = (t - 1) & 1;
        // prefetch bi_{t+4} (rides across lgkm-only barriers)
        const float biE = (t + 4 <= len - 1) ? bival(t + 4) : 0.0f;

        // measurement (1 of 4 iters): max_k log e_{t-1}; hides under matvec
        if ((t & 3) == 3) {
            const float u = __logf(sPrev) + baPrev;  // -inf for dead states: ok
            const float wmx = waveMax(u);
            if (lane == 0) wmB[wv] = wmx;
        }
        // application (1 of 4 iters): shift by max log e_{t-2} (open-loop)
        float r = 0.0f;
        if ((t & 3) == 0) {
            r = fmaxf(wmB[0], wmB[1]);
            M += (double)r;
        }
        const float ba = biA - r;
        const float f = __expf(ba);               // off critical path (early)

        // matvec s_k = sum_i e_i * W[i][k]; e via wave-uniform broadcast float4
        const float4* __restrict__ ev = (const float4*)eLDS[p];
        f32x2 a0 = {0.f, 0.f}, a1 = {0.f, 0.f}, a2 = {0.f, 0.f}, a3 = {0.f, 0.f};
        GRP(W0, 0) GRP(W1, 1) GRP(W2, 2) GRP(W3, 3)
        GRP(W4, 4) GRP(W5, 5) GRP(W6, 6) GRP(W7, 7)
        const f32x2 t01 = a0 + a1, t23 = a2 + a3;
        const f32x2 tt = t01 + t23;
        const float s = tt[0] + tt[1];

        eNew = s * f;                             // the only on-path math
        eLDS[p ^ 1][k] = eNew;

        sPrev = s; baPrev = ba;
        biA = biB; biB = biC; biC = biD; biD = biE;
        lds_barrier();                            // single barrier/step, lgkm-only
    }

    // ---- z = M + log(sum_k e_{len-1}) ----
    const float sm = waveSum(eNew);
    if (lane == 0) redLDS[wv] = sm;
    __syncthreads();
    if (k == 0) zbuf[c] = (float)(M + (double)__logf(redLDS[0] + redLDS[1]));
}

extern "C" __global__ void crf_final_kernel(const float* __restrict__ z,
                                            float* __restrict__ out)
{
    const int b = threadIdx.x;
    out[b] = z[b] - z[b + BB];
}

extern "C" void kernel_launch(void* const* d_in, const int* in_sizes, int n_in,
                              void* d_out, int out_size, void* d_ws, size_t ws_size,
                              hipStream_t stream) {
    const float* em    = (const float*)d_in[0];
    const int*   mask  = (const int*)d_in[1];
    const int*   tgt   = (const int*)d_in[2];
    const float* trans = (const float*)d_in[3];
    const float* start = (const float*)d_in[4];
    const int*   forb  = (const int*)d_in[5];
    float* zbuf = (float*)d_ws;   // 128 per-chain log-partition values

    crf_chain_kernel<<<2 * BB, KK, 0, stream>>>(em, mask, tgt, trans, start, forb, zbuf);
    crf_final_kernel<<<1, BB, 0, stream>>>(zbuf, (float*)d_out);
}